// Round 10
// baseline (225.154 us; speedup 1.0000x reference)
//
#include <hip/hip_runtime.h>
#include <math.h>

#define TS   32
#define PT   36
#define NPIX 1024
#define DF   72      // real feature dim
#define KP   96      // padded K: 3 MFMA k-steps of 32
#define IMH  320
#define IMW  320
#define NTW  10
#define NTILE 100

// ws layout (identical footprint to R3/R5/R6/R9, proven): Fhi | Flo | Sq
#define F_UNITS_PER_TILE 12288           // 64 rt * 3 ks * 4 c * 16 rows
#define FHI_BYTES (NTILE * F_UNITS_PER_TILE * 16)   // 19,660,800
#define SQ_OFF    (2 * FHI_BYTES)                   // 39,321,600 (+409,600 = 39.73 MB)

typedef __attribute__((ext_vector_type(8))) short bf16x8;   // MFMA A/B frag
typedef __attribute__((ext_vector_type(8))) unsigned short u16x8;
typedef __attribute__((ext_vector_type(4))) float f32x4;    // MFMA C/D

// ---------------- kernel A: feature build + split + sqf -------------------
__global__ __launch_bounds__(256)
void nlm_feat_kernel(const float* __restrict__ img,
                     u16x8* __restrict__ Fhi, u16x8* __restrict__ Flo,
                     float* __restrict__ Sq)
{
    __shared__ float Ploc[3][6][36];   // padded rows [2p, 2p+6) of the tile
    __shared__ int   ofsl[KP];
    const int tid  = threadIdx.x;
    const int part = blockIdx.x;    // 0..15
    const int tile = blockIdx.y;
    const int by   = (tile / NTW) * TS;
    const int bx   = (tile % NTW) * TS;
    const float* Pf = &Ploc[0][0][0];

    for (int idx = tid; idx < 3 * 6 * 36; idx += 256) {
        int c   = idx / 216;
        int rem = idx - c * 216;
        int yl  = rem / 36;
        int x   = rem - yl * 36;
        int y   = 2 * part + yl;
        int iy  = min(max(y - 2, 0), TS - 1);
        int ix  = min(max(x - 2, 0), TS - 1);
        Ploc[c][yl][x] = img[(c * IMH + by + iy) * IMW + bx + ix];
    }
    if (tid < KP) {
        int k = tid, v = 0;
        if (k < DF) {
            int c = k / 24, o = k - c * 24;
            int kk = o + (o >= 12);
            int i = kk / 5, j = kk - (kk / 5) * 5;
            v = c * 216 + i * 36 + j;
        }
        ofsl[k] = v;
    }
    __syncthreads();

    if (tid < 64) {
        int m  = part * 64 + tid;
        int my = m >> 5, mx = m & 31;
        int ly0 = my - 2 * part;
        float s = 0.f;
        #pragma unroll
        for (int k = 0; k < 25; ++k) {
            if (k == 12) continue;
            int i = k / 5, j = k - (k / 5) * 5;
            float v0 = Ploc[0][ly0 + i][mx + j];
            float v1 = Ploc[1][ly0 + i][mx + j];
            float v2 = Ploc[2][ly0 + i][mx + j];
            s = fmaf(v0, v0, s); s = fmaf(v1, v1, s); s = fmaf(v2, v2, s);
        }
        Sq[tile * NPIX + m] = s;
    }

    #pragma unroll
    for (int q = 0; q < 3; ++q) {
        int u    = part * 768 + q * 256 + tid;
        int row  = u & 15;
        int c4   = (u >> 4) & 3;
        int rks  = u >> 6;
        int ks   = rks - (rks / 3) * 3;
        int rt   = rks / 3;
        int r    = rt * 16 + row;
        int lbase = ((r >> 5) - 2 * part) * 36 + (r & 31);
        u16x8 h, l;
        #pragma unroll
        for (int j = 0; j < 8; ++j) {
            int k = ks * 32 + c4 * 8 + j;
            unsigned short hs = 0, ls = 0;
            if (k < DF) {
                float f = Pf[lbase + ofsl[k]];
                unsigned int uu = __float_as_uint(f);
                unsigned int hb = uu & 0xffff0000u;
                float lf = f - __uint_as_float(hb);
                hs = (unsigned short)(hb >> 16);
                ls = (unsigned short)(__float_as_uint(lf) >> 16);
            }
            h[j] = hs; l[j] = ls;
        }
        Fhi[tile * F_UNITS_PER_TILE + u] = h;
        Flo[tile * F_UNITS_PER_TILE + u] = l;
    }
}

// -------- pipeline macros: NAMED SCALARS ONLY (no arrays, no lambdas) -----
// R7/R8 lesson: runtime-indexed or address-taken pipeline buffers spill.
// R10: all load addresses are SGPR-base (wvu is readfirstlane-uniform) +
// a per-lane offset computed once -> saddr-form loads, near-zero VALU addr.
#define LOADB(S, it_) do {                                                  \
    const int mt_ = wvu * 16 + (it_);                                       \
    const bf16x8* fh_ = FHt + mt_ * 192;   /* uniform base */               \
    const bf16x8* fl_ = FLt + mt_ * 192;                                    \
    bh##S##_0 = fh_[lane];                                                  \
    bh##S##_1 = fh_[64 + lane];                                             \
    bh##S##_2 = fh_[128 + lane];                                            \
    bl##S##_0 = fl_[lane];                                                  \
    bl##S##_1 = fl_[64 + lane];                                             \
    bl##S##_2 = fl_[128 + lane];                                            \
    sm##S = Sqt[mt_ * 16 + col];                                            \
    /* m>>5 == mt>>1, m&31 == (mt&1)*16 + col  (col<16) */                  \
    const int yoff_ = (by + (mt_ >> 1)) * IMW + bx + ((mt_ & 1) << 4);      \
    ya##S = img[yoff_ + col];                                               \
    yb##S = img[IMH * IMW + yoff_ + col];                                   \
    yc##S = img[2 * IMH * IMW + yoff_ + col];                               \
} while (0)

#define MFMA6(S, K)                                                                      \
    C0 = __builtin_amdgcn_mfma_f32_16x16x32_bf16(aH[0][K], bh##S##_##K, C0, 0, 0, 0);    \
    C1 = __builtin_amdgcn_mfma_f32_16x16x32_bf16(aH[1][K], bh##S##_##K, C1, 0, 0, 0);    \
    C0 = __builtin_amdgcn_mfma_f32_16x16x32_bf16(aH[0][K], bl##S##_##K, C0, 0, 0, 0);    \
    C1 = __builtin_amdgcn_mfma_f32_16x16x32_bf16(aH[1][K], bl##S##_##K, C1, 0, 0, 0);    \
    C0 = __builtin_amdgcn_mfma_f32_16x16x32_bf16(aL[0][K], bh##S##_##K, C0, 0, 0, 0);    \
    C1 = __builtin_amdgcn_mfma_f32_16x16x32_bf16(aL[1][K], bh##S##_##K, C1, 0, 0, 0);

#define COMPUTEB(S, it_) do {                                               \
    f32x4 C0 = {0.f, 0.f, 0.f, 0.f};                                        \
    f32x4 C1 = {0.f, 0.f, 0.f, 0.f};                                        \
    MFMA6(S, 0)                                                             \
    MFMA6(S, 1)                                                             \
    MFMA6(S, 2)                                                             \
    const int m_ = (wvu * 16 + (it_)) * 16 + col;                           \
    _Pragma("unroll")                                                       \
    for (int t = 0; t < 2; ++t) {                                           \
        f32x4 C = t ? C1 : C0;                                              \
        int nb = (rtA + t) * 16 + quad * 4;                                 \
        _Pragma("unroll")                                                   \
        for (int i = 0; i < 4; ++i) {                                       \
            float d2   = fmaxf(sqn[t][i] + sm##S - 2.0f * C[i], 0.f);       \
            float dens = __expf(-__builtin_amdgcn_sqrtf(d2));               \
            if (m_ == nb + i) dens = 0.f;                                   \
            rowsum[t][i] += dens;                                           \
            oacc[t][i][0] = fmaf(dens, ya##S, oacc[t][i][0]);               \
            oacc[t][i][1] = fmaf(dens, yb##S, oacc[t][i][1]);               \
            oacc[t][i][2] = fmaf(dens, yc##S, oacc[t][i][2]);               \
        }                                                                   \
    }                                                                       \
} while (0)

// ---------------- kernel B: MFMA GEMM, m-split across waves ---------------
__global__ __launch_bounds__(256)
__attribute__((amdgpu_waves_per_eu(2, 3)))
void nlm_gemm_kernel(const float* __restrict__ img,
                     const bf16x8* __restrict__ Fhi, const bf16x8* __restrict__ Flo,
                     const float* __restrict__ Sq, float* __restrict__ out)
{
    __shared__ float red[4][32][4];
    const int tid  = threadIdx.x;
    const int lane = tid & 63;
    const int wvu  = __builtin_amdgcn_readfirstlane(tid >> 6);  // SGPR wave id
    const int tile = blockIdx.y;
    const int by   = (tile / NTW) * TS;
    const int bx   = (tile % NTW) * TS;
    const int rtA  = blockIdx.x * 2;
    const int quad = lane >> 4;
    const int col  = lane & 15;

    const bf16x8* FHt = Fhi + tile * F_UNITS_PER_TILE;
    const bf16x8* FLt = Flo + tile * F_UNITS_PER_TILE;
    const float*  Sqt = Sq + tile * NPIX;

    // A fragments — loaded once, pinned
    bf16x8 aH[2][3], aL[2][3];
    #pragma unroll
    for (int t = 0; t < 2; ++t)
        #pragma unroll
        for (int ks = 0; ks < 3; ++ks) {
            int u = ((rtA + t) * 3 + ks) * 64 + lane;
            aH[t][ks] = FHt[u];
            aL[t][ks] = FLt[u];
        }
    asm volatile(""
        : "+v"(aH[0][0]), "+v"(aH[0][1]), "+v"(aH[0][2]),
          "+v"(aH[1][0]), "+v"(aH[1][1]), "+v"(aH[1][2]),
          "+v"(aL[0][0]), "+v"(aL[0][1]), "+v"(aL[0][2]),
          "+v"(aL[1][0]), "+v"(aL[1][1]), "+v"(aL[1][2]));

    float sqn[2][4];
    #pragma unroll
    for (int t = 0; t < 2; ++t)
        #pragma unroll
        for (int i = 0; i < 4; ++i)
            sqn[t][i] = Sqt[(rtA + t) * 16 + quad * 4 + i];

    float rowsum[2][4] = {};
    float oacc[2][4][3] = {};

    // pipeline state: individually named scalars
    bf16x8 bh0_0, bh0_1, bh0_2, bl0_0, bl0_1, bl0_2;
    bf16x8 bh1_0, bh1_1, bh1_2, bl1_0, bl1_1, bl1_2;
    float sm0, ya0, yb0, yc0;
    float sm1, ya1, yb1, yc1;

    LOADB(0, 0);
    #pragma unroll
    for (int p = 0; p < 7; ++p) {
        LOADB(1, 2 * p + 1);
        COMPUTEB(0, 2 * p);
        LOADB(0, 2 * p + 2);
        COMPUTEB(1, 2 * p + 1);
    }
    LOADB(1, 15);
    COMPUTEB(0, 14);
    COMPUTEB(1, 15);

    // in-wave reduce over the 16 column lanes
    #pragma unroll
    for (int mask = 1; mask < 16; mask <<= 1)
        #pragma unroll
        for (int t = 0; t < 2; ++t)
            #pragma unroll
            for (int i = 0; i < 4; ++i) {
                rowsum[t][i]  += __shfl_xor(rowsum[t][i],  mask, 64);
                oacc[t][i][0] += __shfl_xor(oacc[t][i][0], mask, 64);
                oacc[t][i][1] += __shfl_xor(oacc[t][i][1], mask, 64);
                oacc[t][i][2] += __shfl_xor(oacc[t][i][2], mask, 64);
            }

    if (col == 0) {
        #pragma unroll
        for (int t = 0; t < 2; ++t)
            #pragma unroll
            for (int i = 0; i < 4; ++i) {
                int lr = t * 16 + quad * 4 + i;
                red[wvu][lr][0] = rowsum[t][i];
                red[wvu][lr][1] = oacc[t][i][0];
                red[wvu][lr][2] = oacc[t][i][1];
                red[wvu][lr][3] = oacc[t][i][2];
            }
    }
    __syncthreads();

    if (tid < 32) {
        float s = 0.f, o0 = 0.f, o1 = 0.f, o2 = 0.f;
        #pragma unroll
        for (int w = 0; w < 4; ++w) {
            s  += red[w][tid][0];
            o0 += red[w][tid][1];
            o1 += red[w][tid][2];
            o2 += red[w][tid][3];
        }
        int n = rtA * 16 + tid;
        float inv = 1.f / s;
        int gy = by + (n >> 5), gx = bx + (n & 31);
        out[(0 * IMH + gy) * IMW + gx] = o0 * inv;
        out[(1 * IMH + gy) * IMW + gx] = o1 * inv;
        out[(2 * IMH + gy) * IMW + gx] = o2 * inv;
    }
}

extern "C" void kernel_launch(void* const* d_in, const int* in_sizes, int n_in,
                              void* d_out, int out_size, void* d_ws, size_t ws_size,
                              hipStream_t stream) {
    const float* img = (const float*)d_in[0];
    float* out = (float*)d_out;
    char* ws = (char*)d_ws;
    u16x8* Fhi = (u16x8*)ws;
    u16x8* Flo = (u16x8*)(ws + FHI_BYTES);
    float* Sq  = (float*)(ws + SQ_OFF);

    dim3 fgrid(16, NTILE);
    nlm_feat_kernel<<<fgrid, 256, 0, stream>>>(img, Fhi, Flo, Sq);
    dim3 grid(32, NTILE);
    nlm_gemm_kernel<<<grid, 256, 0, stream>>>(img, (const bf16x8*)Fhi,
                                              (const bf16x8*)Flo, Sq, out);
}

// Round 11
// 157.345 us; speedup vs baseline: 1.4310x; 1.4310x over previous
//
#include <hip/hip_runtime.h>
#include <math.h>

#define TS   32
#define PT   36
#define NPIX 1024
#define DF   72      // real feature dim
#define KP   96      // padded K: 3 MFMA k-steps of 32
#define IMH  320
#define IMW  320
#define NTW  10
#define NTILE 100

// ws layout (identical footprint to R3/R5/R6/R9, proven): Fhi | Flo | Sq
#define F_UNITS_PER_TILE 12288           // 64 rt * 3 ks * 4 c * 16 rows
#define FHI_BYTES (NTILE * F_UNITS_PER_TILE * 16)   // 19,660,800
#define SQ_OFF    (2 * FHI_BYTES)                   // 39,321,600 (+409,600 = 39.73 MB)

typedef __attribute__((ext_vector_type(8))) short bf16x8;   // MFMA A/B frag
typedef __attribute__((ext_vector_type(8))) unsigned short u16x8;
typedef __attribute__((ext_vector_type(4))) float f32x4;    // MFMA C/D

// ---------------- kernel A: feature build + split + sqf (unchanged R9) ----
__global__ __launch_bounds__(256)
void nlm_feat_kernel(const float* __restrict__ img,
                     u16x8* __restrict__ Fhi, u16x8* __restrict__ Flo,
                     float* __restrict__ Sq)
{
    __shared__ float Ploc[3][6][36];   // padded rows [2p, 2p+6) of the tile
    __shared__ int   ofsl[KP];
    const int tid  = threadIdx.x;
    const int part = blockIdx.x;    // 0..15
    const int tile = blockIdx.y;
    const int by   = (tile / NTW) * TS;
    const int bx   = (tile % NTW) * TS;
    const float* Pf = &Ploc[0][0][0];

    for (int idx = tid; idx < 3 * 6 * 36; idx += 256) {
        int c   = idx / 216;
        int rem = idx - c * 216;
        int yl  = rem / 36;
        int x   = rem - yl * 36;
        int y   = 2 * part + yl;
        int iy  = min(max(y - 2, 0), TS - 1);
        int ix  = min(max(x - 2, 0), TS - 1);
        Ploc[c][yl][x] = img[(c * IMH + by + iy) * IMW + bx + ix];
    }
    if (tid < KP) {
        int k = tid, v = 0;
        if (k < DF) {
            int c = k / 24, o = k - c * 24;
            int kk = o + (o >= 12);
            int i = kk / 5, j = kk - (kk / 5) * 5;
            v = c * 216 + i * 36 + j;
        }
        ofsl[k] = v;
    }
    __syncthreads();

    if (tid < 64) {
        int m  = part * 64 + tid;
        int my = m >> 5, mx = m & 31;
        int ly0 = my - 2 * part;
        float s = 0.f;
        #pragma unroll
        for (int k = 0; k < 25; ++k) {
            if (k == 12) continue;
            int i = k / 5, j = k - (k / 5) * 5;
            float v0 = Ploc[0][ly0 + i][mx + j];
            float v1 = Ploc[1][ly0 + i][mx + j];
            float v2 = Ploc[2][ly0 + i][mx + j];
            s = fmaf(v0, v0, s); s = fmaf(v1, v1, s); s = fmaf(v2, v2, s);
        }
        Sq[tile * NPIX + m] = s;
    }

    #pragma unroll
    for (int q = 0; q < 3; ++q) {
        int u    = part * 768 + q * 256 + tid;
        int row  = u & 15;
        int c4   = (u >> 4) & 3;
        int rks  = u >> 6;
        int ks   = rks - (rks / 3) * 3;
        int rt   = rks / 3;
        int r    = rt * 16 + row;
        int lbase = ((r >> 5) - 2 * part) * 36 + (r & 31);
        u16x8 h, l;
        #pragma unroll
        for (int j = 0; j < 8; ++j) {
            int k = ks * 32 + c4 * 8 + j;
            unsigned short hs = 0, ls = 0;
            if (k < DF) {
                float f = Pf[lbase + ofsl[k]];
                unsigned int uu = __float_as_uint(f);
                unsigned int hb = uu & 0xffff0000u;
                float lf = f - __uint_as_float(hb);
                hs = (unsigned short)(hb >> 16);
                ls = (unsigned short)(__float_as_uint(lf) >> 16);
            }
            h[j] = hs; l[j] = ls;
        }
        Fhi[tile * F_UNITS_PER_TILE + u] = h;
        Flo[tile * F_UNITS_PER_TILE + u] = l;
    }
}

// ---------------- kernel B: MFMA GEMM, 4 row-tiles per block --------------
// grid (16, 100): block owns 64 rows (4 row-tiles); wave wv sweeps 16 mt.
// Halves B-fragment traffic and per-output loop overhead vs the 2-tile R9.
// Plain R9-style addressing (R10's scalar-base rewrite spilled: 42.8 MB
// WRITE_SIZE). Arrays only with compile-time indices (R7/R8 lesson).
__global__ __launch_bounds__(256)
__attribute__((amdgpu_waves_per_eu(2, 3)))
void nlm_gemm_kernel(const float* __restrict__ img,
                     const bf16x8* __restrict__ Fhi, const bf16x8* __restrict__ Flo,
                     const float* __restrict__ Sq, float* __restrict__ out)
{
    __shared__ float red[4][64][4];
    const int tid  = threadIdx.x;
    const int lane = tid & 63;
    const int wv   = tid >> 6;
    const int tile = blockIdx.y;
    const int by   = (tile / NTW) * TS;
    const int bx   = (tile % NTW) * TS;
    const int rtA  = blockIdx.x * 4;     // block's 4 row-tiles
    const int quad = lane >> 4;
    const int col  = lane & 15;

    const bf16x8* FHt = Fhi + tile * F_UNITS_PER_TILE;
    const bf16x8* FLt = Flo + tile * F_UNITS_PER_TILE;
    const float*  Sqt = Sq + tile * NPIX;

    // A fragments for 4 row-tiles — loaded once, pinned
    bf16x8 aH[4][3], aL[4][3];
    #pragma unroll
    for (int t = 0; t < 4; ++t)
        #pragma unroll
        for (int ks = 0; ks < 3; ++ks) {
            int u = ((rtA + t) * 3 + ks) * 64 + lane;
            aH[t][ks] = FHt[u];
            aL[t][ks] = FLt[u];
        }
    asm volatile(""
        : "+v"(aH[0][0]), "+v"(aH[0][1]), "+v"(aH[0][2]),
          "+v"(aH[1][0]), "+v"(aH[1][1]), "+v"(aH[1][2]),
          "+v"(aH[2][0]), "+v"(aH[2][1]), "+v"(aH[2][2]),
          "+v"(aH[3][0]), "+v"(aH[3][1]), "+v"(aH[3][2]),
          "+v"(aL[0][0]), "+v"(aL[0][1]), "+v"(aL[0][2]),
          "+v"(aL[1][0]), "+v"(aL[1][1]), "+v"(aL[1][2]),
          "+v"(aL[2][0]), "+v"(aL[2][1]), "+v"(aL[2][2]),
          "+v"(aL[3][0]), "+v"(aL[3][1]), "+v"(aL[3][2]));

    float sqn[4][4];
    #pragma unroll
    for (int t = 0; t < 4; ++t)
        #pragma unroll
        for (int i = 0; i < 4; ++i)
            sqn[t][i] = Sqt[(rtA + t) * 16 + quad * 4 + i];

    float rowsum[4][4] = {};
    float oacc[4][4][3] = {};

    #pragma unroll 2
    for (int it = 0; it < 16; ++it) {
        const int mt = wv * 16 + it;
        bf16x8 bH[3], bL[3];
        #pragma unroll
        for (int ks = 0; ks < 3; ++ks) {
            int u = (mt * 3 + ks) * 64 + lane;
            bH[ks] = FHt[u];
            bL[ks] = FLt[u];
        }
        const int m  = mt * 16 + col;
        float sm = Sqt[m];
        int my = m >> 5, mx = m & 31;
        float y0 = img[(0 * IMH + by + my) * IMW + bx + mx];
        float y1 = img[(1 * IMH + by + my) * IMW + bx + mx];
        float y2 = img[(2 * IMH + by + my) * IMW + bx + mx];

        f32x4 C[4];
        #pragma unroll
        for (int t = 0; t < 4; ++t) C[t] = (f32x4){0.f, 0.f, 0.f, 0.f};
        #pragma unroll
        for (int ks = 0; ks < 3; ++ks) {
            #pragma unroll
            for (int t = 0; t < 4; ++t)
                C[t] = __builtin_amdgcn_mfma_f32_16x16x32_bf16(aH[t][ks], bH[ks], C[t], 0, 0, 0);
            #pragma unroll
            for (int t = 0; t < 4; ++t)
                C[t] = __builtin_amdgcn_mfma_f32_16x16x32_bf16(aH[t][ks], bL[ks], C[t], 0, 0, 0);
            #pragma unroll
            for (int t = 0; t < 4; ++t)
                C[t] = __builtin_amdgcn_mfma_f32_16x16x32_bf16(aL[t][ks], bH[ks], C[t], 0, 0, 0);
        }
        #pragma unroll
        for (int t = 0; t < 4; ++t) {
            int nb = (rtA + t) * 16 + quad * 4;
            #pragma unroll
            for (int i = 0; i < 4; ++i) {
                float d2   = fmaxf(sqn[t][i] + sm - 2.0f * C[t][i], 0.f);
                float dens = __expf(-__builtin_amdgcn_sqrtf(d2));
                if (m == nb + i) dens = 0.f;
                rowsum[t][i] += dens;
                oacc[t][i][0] = fmaf(dens, y0, oacc[t][i][0]);
                oacc[t][i][1] = fmaf(dens, y1, oacc[t][i][1]);
                oacc[t][i][2] = fmaf(dens, y2, oacc[t][i][2]);
            }
        }
    }

    // in-wave reduce over the 16 column lanes
    #pragma unroll
    for (int mask = 1; mask < 16; mask <<= 1)
        #pragma unroll
        for (int t = 0; t < 4; ++t)
            #pragma unroll
            for (int i = 0; i < 4; ++i) {
                rowsum[t][i]  += __shfl_xor(rowsum[t][i],  mask, 64);
                oacc[t][i][0] += __shfl_xor(oacc[t][i][0], mask, 64);
                oacc[t][i][1] += __shfl_xor(oacc[t][i][1], mask, 64);
                oacc[t][i][2] += __shfl_xor(oacc[t][i][2], mask, 64);
            }

    if (col == 0) {
        #pragma unroll
        for (int t = 0; t < 4; ++t)
            #pragma unroll
            for (int i = 0; i < 4; ++i) {
                int lr = t * 16 + quad * 4 + i;
                red[wv][lr][0] = rowsum[t][i];
                red[wv][lr][1] = oacc[t][i][0];
                red[wv][lr][2] = oacc[t][i][1];
                red[wv][lr][3] = oacc[t][i][2];
            }
    }
    __syncthreads();

    if (tid < 64) {
        float s = 0.f, o0 = 0.f, o1 = 0.f, o2 = 0.f;
        #pragma unroll
        for (int w = 0; w < 4; ++w) {
            s  += red[w][tid][0];
            o0 += red[w][tid][1];
            o1 += red[w][tid][2];
            o2 += red[w][tid][3];
        }
        int n = rtA * 16 + tid;
        float inv = 1.f / s;
        int gy = by + (n >> 5), gx = bx + (n & 31);
        out[(0 * IMH + gy) * IMW + gx] = o0 * inv;
        out[(1 * IMH + gy) * IMW + gx] = o1 * inv;
        out[(2 * IMH + gy) * IMW + gx] = o2 * inv;
    }
}

extern "C" void kernel_launch(void* const* d_in, const int* in_sizes, int n_in,
                              void* d_out, int out_size, void* d_ws, size_t ws_size,
                              hipStream_t stream) {
    const float* img = (const float*)d_in[0];
    float* out = (float*)d_out;
    char* ws = (char*)d_ws;
    u16x8* Fhi = (u16x8*)ws;
    u16x8* Flo = (u16x8*)(ws + FHI_BYTES);
    float* Sq  = (float*)(ws + SQ_OFF);

    dim3 fgrid(16, NTILE);
    nlm_feat_kernel<<<fgrid, 256, 0, stream>>>(img, Fhi, Flo, Sq);
    dim3 grid(16, NTILE);   // 16 row-groups (64 rows each) x 100 tiles
    nlm_gemm_kernel<<<grid, 256, 0, stream>>>(img, (const bf16x8*)Fhi,
                                              (const bf16x8*)Flo, Sq, out);
}

// Round 12
// 113.928 us; speedup vs baseline: 1.9763x; 1.3811x over previous
//
#include <hip/hip_runtime.h>
#include <math.h>

#define TS   32
#define PT   36
#define NPIX 1024
#define DF   72      // real feature dim
#define KP   96      // padded K: 3 MFMA k-steps of 32
#define IMH  320
#define IMW  320
#define NTW  10
#define NTILE 100

// ws layout offsets unchanged from proven R3..R11 (Flo region now unused)
#define F_UNITS_PER_TILE 12288           // 64 rt * 3 ks * 4 c * 16 rows
#define FHI_BYTES (NTILE * F_UNITS_PER_TILE * 16)   // 19,660,800
#define SQ_OFF    (2 * FHI_BYTES)                   // 39,321,600

#define K2LOG2E 2.0813689810056077f      // (log2 e)^2: exp(-sqrt(x)) = exp2(-sqrt(K2*x))

typedef __attribute__((ext_vector_type(8))) short bf16x8;   // MFMA A/B frag
typedef __attribute__((ext_vector_type(8))) unsigned short u16x8;
typedef __attribute__((ext_vector_type(4))) float f32x4;    // MFMA C/D

// ---------------- kernel A: feature build (RNE bf16) + sqf ----------------
__global__ __launch_bounds__(256)
void nlm_feat_kernel(const float* __restrict__ img,
                     u16x8* __restrict__ Fhi, float* __restrict__ Sq)
{
    __shared__ float Ploc[3][6][36];   // padded rows [2p, 2p+6) of the tile
    __shared__ int   ofsl[KP];
    const int tid  = threadIdx.x;
    const int part = blockIdx.x;    // 0..15
    const int tile = blockIdx.y;
    const int by   = (tile / NTW) * TS;
    const int bx   = (tile % NTW) * TS;
    const float* Pf = &Ploc[0][0][0];

    for (int idx = tid; idx < 3 * 6 * 36; idx += 256) {
        int c   = idx / 216;
        int rem = idx - c * 216;
        int yl  = rem / 36;
        int x   = rem - yl * 36;
        int y   = 2 * part + yl;
        int iy  = min(max(y - 2, 0), TS - 1);
        int ix  = min(max(x - 2, 0), TS - 1);
        Ploc[c][yl][x] = img[(c * IMH + by + iy) * IMW + bx + ix];
    }
    if (tid < KP) {
        int k = tid, v = 0;
        if (k < DF) {
            int c = k / 24, o = k - c * 24;
            int kk = o + (o >= 12);
            int i = kk / 5, j = kk - (kk / 5) * 5;
            v = c * 216 + i * 36 + j;
        }
        ofsl[k] = v;
    }
    __syncthreads();

    if (tid < 64) {
        int m  = part * 64 + tid;
        int my = m >> 5, mx = m & 31;
        int ly0 = my - 2 * part;
        float s = 0.f;
        #pragma unroll
        for (int k = 0; k < 25; ++k) {
            if (k == 12) continue;
            int i = k / 5, j = k - (k / 5) * 5;
            float v0 = Ploc[0][ly0 + i][mx + j];
            float v1 = Ploc[1][ly0 + i][mx + j];
            float v2 = Ploc[2][ly0 + i][mx + j];
            s = fmaf(v0, v0, s); s = fmaf(v1, v1, s); s = fmaf(v2, v2, s);
        }
        Sq[tile * NPIX + m] = s;
    }

    #pragma unroll
    for (int q = 0; q < 3; ++q) {
        int u    = part * 768 + q * 256 + tid;
        int row  = u & 15;
        int c4   = (u >> 4) & 3;
        int rks  = u >> 6;
        int ks   = rks - (rks / 3) * 3;
        int rt   = rks / 3;
        int r    = rt * 16 + row;
        int lbase = ((r >> 5) - 2 * part) * 36 + (r & 31);
        u16x8 h;
        #pragma unroll
        for (int j = 0; j < 8; ++j) {
            int k = ks * 32 + c4 * 8 + j;
            unsigned short hs = 0;
            if (k < DF) {
                float f = Pf[lbase + ofsl[k]];
                unsigned int uu = __float_as_uint(f);
                // round-to-nearest-even bf16 (unbiased; halves truncation error)
                hs = (unsigned short)((uu + 0x7fffu + ((uu >> 16) & 1u)) >> 16);
            }
            h[j] = hs;
        }
        Fhi[tile * F_UNITS_PER_TILE + u] = h;
    }
}

// ---------------- kernel B: single-bf16 MFMA GEMM (R9 2-tile shape) -------
// grid (32, 100): block owns 32 rows (2 row-tiles); wave wv sweeps 16 mt.
// Plain per-iter addressing (R10's scalar-base rewrite spilled); arrays only
// with compile-time indices (R7/R8); no SW pipeline (R9: neutral).
__global__ __launch_bounds__(256)
__attribute__((amdgpu_waves_per_eu(2, 3)))
void nlm_gemm_kernel(const float* __restrict__ img,
                     const bf16x8* __restrict__ Fhi,
                     const float* __restrict__ Sq, float* __restrict__ out)
{
    __shared__ float red[4][32][4];
    const int tid  = threadIdx.x;
    const int lane = tid & 63;
    const int wv   = tid >> 6;
    const int tile = blockIdx.y;
    const int by   = (tile / NTW) * TS;
    const int bx   = (tile % NTW) * TS;
    const int rtA  = blockIdx.x * 2;
    const int quad = lane >> 4;
    const int col  = lane & 15;

    const bf16x8* FHt = Fhi + tile * F_UNITS_PER_TILE;
    const float*  Sqt = Sq + tile * NPIX;

    // A fragments — loaded once, pinned
    bf16x8 aH[2][3];
    #pragma unroll
    for (int t = 0; t < 2; ++t)
        #pragma unroll
        for (int ks = 0; ks < 3; ++ks)
            aH[t][ks] = FHt[((rtA + t) * 3 + ks) * 64 + lane];
    asm volatile(""
        : "+v"(aH[0][0]), "+v"(aH[0][1]), "+v"(aH[0][2]),
          "+v"(aH[1][0]), "+v"(aH[1][1]), "+v"(aH[1][2]));

    // sqn pre-scaled by K2: s2 = sqnK + smK - 2*K2*C
    float sqnK[2][4];
    #pragma unroll
    for (int t = 0; t < 2; ++t)
        #pragma unroll
        for (int i = 0; i < 4; ++i)
            sqnK[t][i] = Sqt[(rtA + t) * 16 + quad * 4 + i] * K2LOG2E;

    float rowsum[2][4] = {};
    float oacc[2][4][3] = {};

    #pragma unroll 2
    for (int it = 0; it < 16; ++it) {
        const int mt = wv * 16 + it;
        bf16x8 bH[3];
        #pragma unroll
        for (int ks = 0; ks < 3; ++ks)
            bH[ks] = FHt[(mt * 3 + ks) * 64 + lane];
        const int m  = mt * 16 + col;
        float smK = Sqt[m] * K2LOG2E;
        int my = m >> 5, mx = m & 31;
        float y0 = img[(0 * IMH + by + my) * IMW + bx + mx];
        float y1 = img[(1 * IMH + by + my) * IMW + bx + mx];
        float y2 = img[(2 * IMH + by + my) * IMW + bx + mx];

        f32x4 C0 = {0.f, 0.f, 0.f, 0.f};
        f32x4 C1 = {0.f, 0.f, 0.f, 0.f};
        #pragma unroll
        for (int ks = 0; ks < 3; ++ks) {
            C0 = __builtin_amdgcn_mfma_f32_16x16x32_bf16(aH[0][ks], bH[ks], C0, 0, 0, 0);
            C1 = __builtin_amdgcn_mfma_f32_16x16x32_bf16(aH[1][ks], bH[ks], C1, 0, 0, 0);
        }
        #pragma unroll
        for (int t = 0; t < 2; ++t) {
            f32x4 C = t ? C1 : C0;
            int nb = (rtA + t) * 16 + quad * 4;
            #pragma unroll
            for (int i = 0; i < 4; ++i) {
                float s2   = fmaxf(fmaf(-2.0f * K2LOG2E, C[i], sqnK[t][i] + smK), 0.f);
                // exp(-sqrt(d2)) == exp2(-sqrt(K2*d2)); negate via source mod
                float dens = __builtin_amdgcn_exp2f(-__builtin_amdgcn_sqrtf(s2));
                if (m == nb + i) dens = 0.f;
                rowsum[t][i] += dens;
                oacc[t][i][0] = fmaf(dens, y0, oacc[t][i][0]);
                oacc[t][i][1] = fmaf(dens, y1, oacc[t][i][1]);
                oacc[t][i][2] = fmaf(dens, y2, oacc[t][i][2]);
            }
        }
    }

    // in-wave reduce over the 16 column lanes
    #pragma unroll
    for (int mask = 1; mask < 16; mask <<= 1)
        #pragma unroll
        for (int t = 0; t < 2; ++t)
            #pragma unroll
            for (int i = 0; i < 4; ++i) {
                rowsum[t][i]  += __shfl_xor(rowsum[t][i],  mask, 64);
                oacc[t][i][0] += __shfl_xor(oacc[t][i][0], mask, 64);
                oacc[t][i][1] += __shfl_xor(oacc[t][i][1], mask, 64);
                oacc[t][i][2] += __shfl_xor(oacc[t][i][2], mask, 64);
            }

    if (col == 0) {
        #pragma unroll
        for (int t = 0; t < 2; ++t)
            #pragma unroll
            for (int i = 0; i < 4; ++i) {
                int lr = t * 16 + quad * 4 + i;
                red[wv][lr][0] = rowsum[t][i];
                red[wv][lr][1] = oacc[t][i][0];
                red[wv][lr][2] = oacc[t][i][1];
                red[wv][lr][3] = oacc[t][i][2];
            }
    }
    __syncthreads();

    if (tid < 32) {
        float s = 0.f, o0 = 0.f, o1 = 0.f, o2 = 0.f;
        #pragma unroll
        for (int w = 0; w < 4; ++w) {
            s  += red[w][tid][0];
            o0 += red[w][tid][1];
            o1 += red[w][tid][2];
            o2 += red[w][tid][3];
        }
        int n = rtA * 16 + tid;
        float inv = 1.f / s;
        int gy = by + (n >> 5), gx = bx + (n & 31);
        out[(0 * IMH + gy) * IMW + gx] = o0 * inv;
        out[(1 * IMH + gy) * IMW + gx] = o1 * inv;
        out[(2 * IMH + gy) * IMW + gx] = o2 * inv;
    }
}

extern "C" void kernel_launch(void* const* d_in, const int* in_sizes, int n_in,
                              void* d_out, int out_size, void* d_ws, size_t ws_size,
                              hipStream_t stream) {
    const float* img = (const float*)d_in[0];
    float* out = (float*)d_out;
    char* ws = (char*)d_ws;
    u16x8* Fhi = (u16x8*)ws;
    float* Sq  = (float*)(ws + SQ_OFF);

    dim3 fgrid(16, NTILE);
    nlm_feat_kernel<<<fgrid, 256, 0, stream>>>(img, Fhi, Sq);
    dim3 grid(32, NTILE);
    nlm_gemm_kernel<<<grid, 256, 0, stream>>>(img, (const bf16x8*)Fhi, Sq, out);
}